// Round 11
// baseline (200.414 us; speedup 1.0000x reference)
//
#include <hip/hip_runtime.h>
#include <math.h>

#define T_STEPS 256
#define BS      512
#define N       2048
#define BLOCK   256               // 4 waves per batch element -> 2 waves/SIMD
#define NWAVE   (BLOCK / 64)      // 4
#define EPT     (N / BLOCK)       // 8 elements per thread
#define FUDGE   1e-4f

typedef float vfloat4 __attribute__((ext_vector_type(4)));

// Non-rematerializable 16B load: INLINEASM defs cannot be sunk into the loop
// or re-executed by the scheduler (plain loads were: VGPR_Count 36 in R9 with
// 24 live coefficient floats -> 48 KB/CU/step of L1 reload traffic).
__device__ __forceinline__ vfloat4 load_pin_f4(const void* p) {
    vfloat4 r;
    asm volatile("global_load_dwordx4 %0, %1, off" : "=v"(r) : "v"(p) : "memory");
    return r;
}

#define PIN8(A) asm volatile("" \
    : "+v"((A)[0]), "+v"((A)[1]), "+v"((A)[2]), "+v"((A)[3]), \
      "+v"((A)[4]), "+v"((A)[5]), "+v"((A)[6]), "+v"((A)[7]))

// --- wave64 sum via DPP: lane 63 holds the wave total --------------------
template <int CTRL>
__device__ __forceinline__ float dpp_add(float v) {
    int sh = __builtin_amdgcn_update_dpp(0, __float_as_int(v), CTRL, 0xf, 0xf, true);
    return v + __int_as_float(sh);
}

__device__ __forceinline__ float wave_sum_lane63(float v) {
    v = dpp_add<0x111>(v);  // row_shr:1
    v = dpp_add<0x112>(v);  // row_shr:2
    v = dpp_add<0x114>(v);  // row_shr:4
    v = dpp_add<0x118>(v);  // row_shr:8
    v = dpp_add<0x142>(v);  // row_bcast:15
    v = dpp_add<0x143>(v);  // row_bcast:31
    return v;
}

// 4-wave block per batch element; coefficients pinned in VGPRs via asm loads.
// R10 bug fixed here: the s_waitcnt must be DATA-TIED to the loaded values
// ("+v" in/out operands) -- a standalone waitcnt asm does not order the
// consuming arithmetic after the wait, so unpack FMAs read pre-writeback
// garbage (NaN). hbase for step t+1 is computed in the barrier-wait window.
// w_out scaled: w_t = sp_t*v_t, sp_t = wd^t => update is one fma;
// norms = sqrt(FUDGE + (e*lr)^2 * sum h^2) (algebraically = reference).
__global__ __launch_bounds__(BLOCK, 2)
void legacy_elbo_scan_kernel(
    const float* __restrict__ noises,   // [T, BS]
    const float* __restrict__ ys,       // [T]
    const float* __restrict__ qs,       // [T]
    const float* __restrict__ z_biases, // [N]
    const float* __restrict__ w_in,     // [N]
    const float* __restrict__ w_inq,    // [N]
    const float* __restrict__ p_llr,
    const float* __restrict__ p_llrd,
    const float* __restrict__ p_sigb,
    const float* __restrict__ p_oscale,
    const float* __restrict__ p_ufs,
    const float* __restrict__ p_lwd,
    const float* __restrict__ p_qscale,
    const float* __restrict__ p_tauq,
    const float* __restrict__ p_tauy,
    float* __restrict__ out)            // [T, BS]
{
    const int tid  = threadIdx.x;
    const int lane = tid & 63;
    const int wid  = tid >> 6;          // 0..3
    const int blk  = blockIdx.x;        // batch index k

    __shared__ float ys_s[T_STEPS];
    __shared__ float qs_s[T_STEPS];
    __shared__ float nz_s[T_STEPS];
    __shared__ float red[2][2 * NWAVE];  // [parity][wave*2 + {su,sh2}]

    // Pinned coefficient loads (coalesced 16B/lane).
    const float4* zb4 = (const float4*)z_biases;
    const float4* wi4 = (const float4*)w_in;
    const float4* wq4 = (const float4*)w_inq;
    vfloat4 b0 = load_pin_f4(zb4 + tid);
    vfloat4 b1 = load_pin_f4(zb4 + tid + BLOCK);
    vfloat4 w0 = load_pin_f4(wi4 + tid);
    vfloat4 w1 = load_pin_f4(wi4 + tid + BLOCK);
    vfloat4 g0 = load_pin_f4(wq4 + tid);
    vfloat4 g1 = load_pin_f4(wq4 + tid + BLOCK);

    // Per-step scalars: T == BLOCK, one element per thread.
    ys_s[tid] = ys[tid];
    qs_s[tid] = qs[tid];
    nz_s[tid] = noises[tid * BS + blk];

    const float sigb    = p_sigb[0];
    const float llr     = p_llr[0];
    const float llrd    = p_llrd[0];
    const float oscale  = p_oscale[0];
    const float ufs     = p_ufs[0];
    const float lwd     = p_lwd[0];
    const float qscale  = p_qscale[0];
    const float tauq_m1 = p_tauq[0];
    const float tauy_m1 = p_tauy[0];

    const float lr0      = expf(llr);
    const float lr_decay = expf(llrd);
    const float wd       = expf(lwd);
    const float rwd      = 1.0f / wd;
    const float tauq     = 1.0f + log1pf(expf(tauq_m1));
    const float tauy     = 1.0f + log1pf(expf(tauy_m1));
    const float omtq     = 1.0f - tauq;
    const float omty     = 1.0f - tauy;

    // Drain the asm loads, DATA-TIED: every later use of b0..g1 depends on
    // this asm's outputs, so nothing can read the registers pre-writeback.
    asm volatile("s_waitcnt vmcnt(0)"
        : "+v"(b0), "+v"(b1), "+v"(w0), "+v"(w1), "+v"(g0), "+v"(g1)
        :
        : "memory");

    // Unpack into scalar arrays and pin (scaled bias, w, g stay resident).
    float bs_[EPT] = {sigb*b0.x, sigb*b0.y, sigb*b0.z, sigb*b0.w,
                      sigb*b1.x, sigb*b1.y, sigb*b1.z, sigb*b1.w};
    float cw[EPT]  = {w0.x, w0.y, w0.z, w0.w, w1.x, w1.y, w1.z, w1.w};
    float cg[EPT]  = {g0.x, g0.y, g0.z, g0.w, g1.x, g1.y, g1.z, g1.w};
    PIN8(bs_); PIN8(cw); PIN8(cg);

    // Persistent per-thread state.
    float v[EPT];
#pragma unroll
    for (int i = 0; i < EPT; ++i) v[i] = 0.0f;

    float u = 0.0f, e = 0.0f, lr_mult = 1.0f, ylp = 0.0f;
    float sp = 1.0f, rsp = 1.0f;        // wd^t and 1/wd^t

    __syncthreads();

    // Pipeline prologue: qlp/hb for step 0.
    float qlp = tauq * qs_s[0];         // omtq*0 + tauq*q0
    float qsc = qscale * qlp;
    float hb[EPT];
#pragma unroll
    for (int i = 0; i < EPT; ++i) hb[i] = fmaf(qsc, cg[i], bs_[i]);

    float y_c = ys_s[0], n_c = nz_s[0];

    for (int t = 0; t < T_STEPS; ++t) {
        const int tn = (t + 1 < T_STEPS) ? t + 1 : t;
        const float q_n = qs_s[tn], y_n = ys_s[tn], n_n = nz_s[tn];

        const float x = fmaf(u, ufs, e) + n_c;

        float su0 = 0.f, su1 = 0.f, sh0 = 0.f, sh1 = 0.f;
        float h[EPT];
#pragma unroll
        for (int i = 0; i < EPT; ++i) {
            const float hv = fmaxf(fmaf(x, cw[i], hb[i]), 0.0f);
            h[i] = hv;
            if (i & 1) { su1 = fmaf(v[i], hv, su1); sh1 = fmaf(hv, hv, sh1); }
            else       { su0 = fmaf(v[i], hv, su0); sh0 = fmaf(hv, hv, sh0); }
        }
        float su_w = wave_sum_lane63(su0 + su1);
        float sh_w = wave_sum_lane63(sh0 + sh1);

        const int p = t & 1;
        if (lane == 63) {
            red[p][wid * 2]     = su_w;
            red[p][wid * 2 + 1] = sh_w;
        }

        // Fill the barrier-wait window: next step's qlp/qsc/hbase
        // (scalar-input-only, independent of this step's reduction).
        qlp = omtq * qlp + tauq * q_n;
        qsc = qscale * qlp;
#pragma unroll
        for (int i = 0; i < EPT; ++i) hb[i] = fmaf(qsc, cg[i], bs_[i]);

        __syncthreads();                // single barrier per step (parity-safe)
        const float4 r0 = *(const float4*)&red[p][0];
        const float4 r1 = *(const float4*)&red[p][4];
        const float su_t = (r0.x + r0.z) + (r1.x + r1.z);
        const float sh2  = (r0.y + r0.w) + (r1.y + r1.w);

        u = sp * su_t;                  // w_t = sp * v_t
        if (tid == 0) out[t * BS + blk] = oscale * u;

        ylp = omty * ylp + tauy * y_c;
        e = ylp - u;
        const float el = e * (lr0 * lr_mult);
        const float c  = el * rsp;      // dw coefficient in v-space

#pragma unroll
        for (int i = 0; i < EPT; ++i)
            v[i] = fmaf(c, h[i], v[i]);

        const float nrm = sqrtf(fmaf(el * el, sh2, FUDGE));
        lr_mult *= __expf(-lr_decay * nrm);
        sp  *= wd;
        rsp *= rwd;

        y_c = y_n; n_c = n_n;
    }
}

extern "C" void kernel_launch(void* const* d_in, const int* in_sizes, int n_in,
                              void* d_out, int out_size, void* d_ws, size_t ws_size,
                              hipStream_t stream) {
    (void)in_sizes; (void)n_in; (void)d_ws; (void)ws_size; (void)out_size;
    const float* noises   = (const float*)d_in[0];
    const float* ys       = (const float*)d_in[1];
    const float* qs       = (const float*)d_in[2];
    const float* z_biases = (const float*)d_in[3];
    const float* w_in     = (const float*)d_in[4];
    const float* w_inq    = (const float*)d_in[5];
    const float* llr      = (const float*)d_in[6];
    const float* llrd     = (const float*)d_in[7];
    const float* sigb     = (const float*)d_in[8];
    const float* oscale   = (const float*)d_in[9];
    const float* ufs      = (const float*)d_in[10];
    const float* lwd      = (const float*)d_in[11];
    const float* qscale   = (const float*)d_in[12];
    const float* tauq     = (const float*)d_in[13];
    const float* tauy     = (const float*)d_in[14];
    float* out = (float*)d_out;

    hipLaunchKernelGGL(legacy_elbo_scan_kernel, dim3(BS), dim3(BLOCK), 0, stream,
                       noises, ys, qs, z_biases, w_in, w_inq,
                       llr, llrd, sigb, oscale, ufs, lwd, qscale, tauq, tauy,
                       out);
}

// Round 12
// 199.136 us; speedup vs baseline: 1.0064x; 1.0064x over previous
//
#include <hip/hip_runtime.h>
#include <math.h>

#define T_STEPS 256
#define BS      512
#define N       2048
#define BLOCK   256               // 4 waves per batch element -> 2 waves/SIMD
#define NWAVE   (BLOCK / 64)      // 4
#define EPT     (N / BLOCK)       // 8 elements per thread
#define FUDGE   1e-4f

typedef float vfloat4 __attribute__((ext_vector_type(4)));

// Non-rematerializable 16B load (INLINEASM defs can't be re-executed).
__device__ __forceinline__ vfloat4 load_pin_f4(const void* p) {
    vfloat4 r;
    asm volatile("global_load_dwordx4 %0, %1, off" : "=v"(r) : "v"(p) : "memory");
    return r;
}

#define PIN8(A) asm volatile("" \
    : "+v"((A)[0]), "+v"((A)[1]), "+v"((A)[2]), "+v"((A)[3]), \
      "+v"((A)[4]), "+v"((A)[5]), "+v"((A)[6]), "+v"((A)[7]))

// --- wave64 sum via DPP: lane 63 holds the wave total --------------------
template <int CTRL>
__device__ __forceinline__ float dpp_add(float v) {
    int sh = __builtin_amdgcn_update_dpp(0, __float_as_int(v), CTRL, 0xf, 0xf, true);
    return v + __int_as_float(sh);
}

__device__ __forceinline__ float wave_sum_lane63(float v) {
    v = dpp_add<0x111>(v);  // row_shr:1
    v = dpp_add<0x112>(v);  // row_shr:2
    v = dpp_add<0x114>(v);  // row_shr:4
    v = dpp_add<0x118>(v);  // row_shr:8
    v = dpp_add<0x142>(v);  // row_bcast:15
    v = dpp_add<0x143>(v);  // row_bcast:31
    return v;
}

// R11 post-mortem: VGPR_Count=40 == exactly the dynamic state; the 24
// asm-loaded coefficients were spilled to scratch and reloaded every step.
// __launch_bounds__'s 2nd arg is only the occupancy FLOOR; the allocator's
// pressure target follows the occupancy CEILING. amdgpu_waves_per_eu(2,2)
// pins the ceiling to the truth (2 waves/EU = 2 blocks/CU) -> 256-VGPR
// budget -> ~64 live regs fit with no spill (R6 proved this attribute moves
// the allocator; it failed there only because EPT=32 needed ~190 regs).
__global__ __attribute__((amdgpu_waves_per_eu(2, 2))) __launch_bounds__(BLOCK)
void legacy_elbo_scan_kernel(
    const float* __restrict__ noises,   // [T, BS]
    const float* __restrict__ ys,       // [T]
    const float* __restrict__ qs,       // [T]
    const float* __restrict__ z_biases, // [N]
    const float* __restrict__ w_in,     // [N]
    const float* __restrict__ w_inq,    // [N]
    const float* __restrict__ p_llr,
    const float* __restrict__ p_llrd,
    const float* __restrict__ p_sigb,
    const float* __restrict__ p_oscale,
    const float* __restrict__ p_ufs,
    const float* __restrict__ p_lwd,
    const float* __restrict__ p_qscale,
    const float* __restrict__ p_tauq,
    const float* __restrict__ p_tauy,
    float* __restrict__ out)            // [T, BS]
{
    const int tid  = threadIdx.x;
    const int lane = tid & 63;
    const int wid  = tid >> 6;          // 0..3
    const int blk  = blockIdx.x;        // batch index k

    __shared__ float ys_s[T_STEPS];
    __shared__ float qs_s[T_STEPS];
    __shared__ float nz_s[T_STEPS];
    __shared__ float red[2][2 * NWAVE];  // [parity][wave*2 + {su,sh2}]

    // Pinned coefficient loads (coalesced 16B/lane).
    const float4* zb4 = (const float4*)z_biases;
    const float4* wi4 = (const float4*)w_in;
    const float4* wq4 = (const float4*)w_inq;
    vfloat4 b0 = load_pin_f4(zb4 + tid);
    vfloat4 b1 = load_pin_f4(zb4 + tid + BLOCK);
    vfloat4 w0 = load_pin_f4(wi4 + tid);
    vfloat4 w1 = load_pin_f4(wi4 + tid + BLOCK);
    vfloat4 g0 = load_pin_f4(wq4 + tid);
    vfloat4 g1 = load_pin_f4(wq4 + tid + BLOCK);

    // Per-step scalars: T == BLOCK, one element per thread.
    ys_s[tid] = ys[tid];
    qs_s[tid] = qs[tid];
    nz_s[tid] = noises[tid * BS + blk];

    const float sigb    = p_sigb[0];
    const float llr     = p_llr[0];
    const float llrd    = p_llrd[0];
    const float oscale  = p_oscale[0];
    const float ufs     = p_ufs[0];
    const float lwd     = p_lwd[0];
    const float qscale  = p_qscale[0];
    const float tauq_m1 = p_tauq[0];
    const float tauy_m1 = p_tauy[0];

    const float lr0      = expf(llr);
    const float lr_decay = expf(llrd);
    const float wd       = expf(lwd);
    const float rwd      = 1.0f / wd;
    const float tauq     = 1.0f + log1pf(expf(tauq_m1));
    const float tauy     = 1.0f + log1pf(expf(tauy_m1));
    const float omtq     = 1.0f - tauq;
    const float omty     = 1.0f - tauy;

    // Drain the asm loads, DATA-TIED (R10 lesson): all later uses of b0..g1
    // depend on this asm's outputs -> no pre-writeback reads.
    asm volatile("s_waitcnt vmcnt(0)"
        : "+v"(b0), "+v"(b1), "+v"(w0), "+v"(w1), "+v"(g0), "+v"(g1)
        :
        : "memory");

    // Unpack into scalar arrays and pin (scaled bias, w, g stay resident).
    float bs_[EPT] = {sigb*b0.x, sigb*b0.y, sigb*b0.z, sigb*b0.w,
                      sigb*b1.x, sigb*b1.y, sigb*b1.z, sigb*b1.w};
    float cw[EPT]  = {w0.x, w0.y, w0.z, w0.w, w1.x, w1.y, w1.z, w1.w};
    float cg[EPT]  = {g0.x, g0.y, g0.z, g0.w, g1.x, g1.y, g1.z, g1.w};
    PIN8(bs_); PIN8(cw); PIN8(cg);

    // Persistent per-thread state.
    float v[EPT];
#pragma unroll
    for (int i = 0; i < EPT; ++i) v[i] = 0.0f;

    float u = 0.0f, e = 0.0f, lr_mult = 1.0f, ylp = 0.0f;
    float sp = 1.0f, rsp = 1.0f;        // wd^t and 1/wd^t

    __syncthreads();

    // Pipeline prologue: qlp/hb for step 0.
    float qlp = tauq * qs_s[0];         // omtq*0 + tauq*q0
    float qsc = qscale * qlp;
    float hb[EPT];
#pragma unroll
    for (int i = 0; i < EPT; ++i) hb[i] = fmaf(qsc, cg[i], bs_[i]);

    float y_c = ys_s[0], n_c = nz_s[0];

    for (int t = 0; t < T_STEPS; ++t) {
        const int tn = (t + 1 < T_STEPS) ? t + 1 : t;
        const float q_n = qs_s[tn], y_n = ys_s[tn], n_n = nz_s[tn];

        const float x = fmaf(u, ufs, e) + n_c;

        float su0 = 0.f, su1 = 0.f, sh0 = 0.f, sh1 = 0.f;
        float h[EPT];
#pragma unroll
        for (int i = 0; i < EPT; ++i) {
            const float hv = fmaxf(fmaf(x, cw[i], hb[i]), 0.0f);
            h[i] = hv;
            if (i & 1) { su1 = fmaf(v[i], hv, su1); sh1 = fmaf(hv, hv, sh1); }
            else       { su0 = fmaf(v[i], hv, su0); sh0 = fmaf(hv, hv, sh0); }
        }
        float su_w = wave_sum_lane63(su0 + su1);
        float sh_w = wave_sum_lane63(sh0 + sh1);

        const int p = t & 1;
        if (lane == 63) {
            red[p][wid * 2]     = su_w;
            red[p][wid * 2 + 1] = sh_w;
        }

        // Fill the barrier-wait window: next step's qlp/qsc/hbase
        // (scalar-input-only, independent of this step's reduction).
        qlp = omtq * qlp + tauq * q_n;
        qsc = qscale * qlp;
#pragma unroll
        for (int i = 0; i < EPT; ++i) hb[i] = fmaf(qsc, cg[i], bs_[i]);

        __syncthreads();                // single barrier per step (parity-safe)
        const float4 r0 = *(const float4*)&red[p][0];
        const float4 r1 = *(const float4*)&red[p][4];
        const float su_t = (r0.x + r0.z) + (r1.x + r1.z);
        const float sh2  = (r0.y + r0.w) + (r1.y + r1.w);

        u = sp * su_t;                  // w_t = sp * v_t
        if (tid == 0) out[t * BS + blk] = oscale * u;

        ylp = omty * ylp + tauy * y_c;
        e = ylp - u;
        const float el = e * (lr0 * lr_mult);
        const float c  = el * rsp;      // dw coefficient in v-space

#pragma unroll
        for (int i = 0; i < EPT; ++i)
            v[i] = fmaf(c, h[i], v[i]);

        const float nrm = sqrtf(fmaf(el * el, sh2, FUDGE));
        lr_mult *= __expf(-lr_decay * nrm);
        sp  *= wd;
        rsp *= rwd;

        y_c = y_n; n_c = n_n;
    }
}

extern "C" void kernel_launch(void* const* d_in, const int* in_sizes, int n_in,
                              void* d_out, int out_size, void* d_ws, size_t ws_size,
                              hipStream_t stream) {
    (void)in_sizes; (void)n_in; (void)d_ws; (void)ws_size; (void)out_size;
    const float* noises   = (const float*)d_in[0];
    const float* ys       = (const float*)d_in[1];
    const float* qs       = (const float*)d_in[2];
    const float* z_biases = (const float*)d_in[3];
    const float* w_in     = (const float*)d_in[4];
    const float* w_inq    = (const float*)d_in[5];
    const float* llr      = (const float*)d_in[6];
    const float* llrd     = (const float*)d_in[7];
    const float* sigb     = (const float*)d_in[8];
    const float* oscale   = (const float*)d_in[9];
    const float* ufs      = (const float*)d_in[10];
    const float* lwd      = (const float*)d_in[11];
    const float* qscale   = (const float*)d_in[12];
    const float* tauq     = (const float*)d_in[13];
    const float* tauy     = (const float*)d_in[14];
    float* out = (float*)d_out;

    hipLaunchKernelGGL(legacy_elbo_scan_kernel, dim3(BS), dim3(BLOCK), 0, stream,
                       noises, ys, qs, z_biases, w_in, w_inq,
                       llr, llrd, sigb, oscale, ufs, lwd, qscale, tauq, tauy,
                       out);
}